// Round 2
// baseline (1415.246 us; speedup 1.0000x reference)
//
#include <hip/hip_runtime.h>
#include <hip/hip_bf16.h>
#include <cstdint>
#include <cstddef>

#define BATCH 16
#define CH 64
#define HWN 65536
#define NBLK 64          // blocks per batch in proj_s
#define CHUNK 256        // pixels per chunk (= blockDim)
#define NCHUNK 4         // chunks per block -> 1024 px/block
#define LSTRIDE 68       // padded bf16 row stride (64 -> 68) : 4-way write, 0-way read

// ---------------- workspace layout (bytes) ----------------
// Sp: [B*NBLK][4096] f32  (split-K partial S)   16 MB
// Zp: [B*NBLK][4][64] f32 (split-K partial Z)    1 MB
// M : [B][64][64] f32     (normalized sim)     256 KB
static const size_t SP_OFF = 0;
static const size_t ZP_OFF = SP_OFF + (size_t)BATCH * NBLK * 4096 * 4;
static const size_t M_OFF  = ZP_OFF + (size_t)BATCH * NBLK * 4 * 64 * 4;

__device__ __forceinline__ void unpack4(uint2 u, float* f) {
    f[0] = __uint_as_float(u.x << 16);
    f[1] = __uint_as_float(u.x & 0xffff0000u);
    f[2] = __uint_as_float(u.y << 16);
    f[3] = __uint_as_float(u.y & 0xffff0000u);
}

__device__ __forceinline__ uint pack2(float a, float b) {
    // round-to-nearest-even bf16 pack
    ushort lo = __bfloat16_as_ushort(__float2bfloat16(a));
    ushort hi = __bfloat16_as_ushort(__float2bfloat16(b));
    return (uint)lo | ((uint)hi << 16);
}

// ---------------------------------------------------------------------------
// Fused kernel: theta/phi projection (fp32, per-pixel thread) -> bf16 LDS
// staging -> per-wave 8x8 outer-product accumulation of
//   S[c,d] = sum_n P[c,n]*E[d,n],  Z[d] = sum_n E[d,n],  E = exp(theta_out).
// Split-K over NBLK blocks per batch; deterministic partials, no atomics.
// exp without max-subtract is safe: theta_out ~ N(0,1), max ~5.8 sigma -> e^6.
// ---------------------------------------------------------------------------
__global__ __launch_bounds__(256) void proj_s(
    const float* __restrict__ x,
    const float* __restrict__ thw, const float* __restrict__ thb,
    const float* __restrict__ phw, const float* __restrict__ phb,
    float* __restrict__ Sp, float* __restrict__ Zp)
{
    __shared__ __align__(16) ushort smem[2 * CHUNK * LSTRIDE];   // ps, es (69.6 KB)
    ushort* ps = smem;
    ushort* es = smem + CHUNK * LSTRIDE;

    const int b   = blockIdx.y;
    const int blk = blockIdx.x;
    const int tid = threadIdx.x;
    const int wid = tid >> 6;
    const int l   = tid & 63;
    const int c0  = (l & 7) * 8;
    const int d0  = (l >> 3) * 8;

    float acc[8][8];
#pragma unroll
    for (int i = 0; i < 8; i++)
#pragma unroll
        for (int j = 0; j < 8; j++) acc[i][j] = 0.f;
    float z[8];
#pragma unroll
    for (int j = 0; j < 8; j++) z[j] = 0.f;

    const float* xb = x + (size_t)b * CH * HWN;

    for (int chk = 0; chk < NCHUNK; chk++) {
        const int n = blk * (CHUNK * NCHUNK) + chk * CHUNK + tid;

        // ---- phase 1: per-pixel theta/phi projection, stage bf16 to LDS ----
        float xr[CH];
#pragma unroll
        for (int c = 0; c < CH; c++) xr[c] = xb[(size_t)c * HWN + n];

        ushort* prow = ps + tid * LSTRIDE;
        ushort* erow = es + tid * LSTRIDE;

#pragma unroll 1
        for (int o = 0; o < CH; o += 4) {
            float ta0 = thb[o], ta1 = thb[o + 1], ta2 = thb[o + 2], ta3 = thb[o + 3];
            float pa0 = phb[o], pa1 = phb[o + 1], pa2 = phb[o + 2], pa3 = phb[o + 3];
            const float* tw = thw + o * CH;
            const float* pw = phw + o * CH;
#pragma unroll
            for (int c = 0; c < CH; c++) {
                const float xv = xr[c];
                ta0 = fmaf(tw[c],          xv, ta0);
                ta1 = fmaf(tw[CH + c],     xv, ta1);
                ta2 = fmaf(tw[2 * CH + c], xv, ta2);
                ta3 = fmaf(tw[3 * CH + c], xv, ta3);
                pa0 = fmaf(pw[c],          xv, pa0);
                pa1 = fmaf(pw[CH + c],     xv, pa1);
                pa2 = fmaf(pw[2 * CH + c], xv, pa2);
                pa3 = fmaf(pw[3 * CH + c], xv, pa3);
            }
            uint2 ev, pv;
            ev.x = pack2(__expf(ta0), __expf(ta1));
            ev.y = pack2(__expf(ta2), __expf(ta3));
            pv.x = pack2(pa0, pa1);
            pv.y = pack2(pa2, pa3);
            *(uint2*)(erow + o) = ev;     // 8B LDS write, 8-aligned (o%4==0)
            *(uint2*)(prow + o) = pv;
        }
        __syncthreads();

        // ---- phase 2: wave-level outer products over this wave's 64 px ----
        const ushort* pbase = ps + (wid * 64) * LSTRIDE;
        const ushort* ebase = es + (wid * 64) * LSTRIDE;
#pragma unroll 4
        for (int px = 0; px < 64; px++) {
            uint2 up0 = *(const uint2*)(pbase + px * LSTRIDE + c0);
            uint2 up1 = *(const uint2*)(pbase + px * LSTRIDE + c0 + 4);
            uint2 ue0 = *(const uint2*)(ebase + px * LSTRIDE + d0);
            uint2 ue1 = *(const uint2*)(ebase + px * LSTRIDE + d0 + 4);
            float a[8], e[8];
            unpack4(up0, a);
            unpack4(up1, a + 4);
            unpack4(ue0, e);
            unpack4(ue1, e + 4);
#pragma unroll
            for (int j = 0; j < 8; j++) z[j] += e[j];
#pragma unroll
            for (int ii = 0; ii < 8; ii++)
#pragma unroll
                for (int j = 0; j < 8; j++) acc[ii][j] = fmaf(a[ii], e[j], acc[ii][j]);
        }
        __syncthreads();
    }

    // ---- block reduce: 4 waves -> one 64x64 tile (reuse smem as f32) ----
    float* red = (float*)smem;
    for (int w = 0; w < 4; w++) {
        if (wid == w) {
            if (w == 0) {
#pragma unroll
                for (int ii = 0; ii < 8; ii++)
#pragma unroll
                    for (int j = 0; j < 8; j++)
                        red[(c0 + ii) * 64 + d0 + j] = acc[ii][j];
            } else {
#pragma unroll
                for (int ii = 0; ii < 8; ii++)
#pragma unroll
                    for (int j = 0; j < 8; j++)
                        red[(c0 + ii) * 64 + d0 + j] += acc[ii][j];
            }
        }
        __syncthreads();
    }
    const int gblk = b * NBLK + blk;
    float* sp = Sp + (size_t)gblk * 4096;
    for (int k = tid; k < 4096; k += 256) sp[k] = red[k];

    // Z partials: lanes sharing d0 hold identical z[]; leader writes per wave.
    if ((l & 7) == 0) {
        float* zp = Zp + ((size_t)gblk * 4 + wid) * 64 + d0;
#pragma unroll
        for (int j = 0; j < 8; j++) zp[j] = z[j];
    }
}

// ---------------------------------------------------------------------------
// Reduce split-K partials; M[b,c,d] = S[b,c,d] / Z[b,d]
// ---------------------------------------------------------------------------
__global__ __launch_bounds__(256) void normalize_S(
    const float* __restrict__ Sp, const float* __restrict__ Zp,
    float* __restrict__ M)
{
    const int b   = blockIdx.x;
    const int tid = threadIdx.x;
    __shared__ float Zl[64];
    if (tid < 64) {
        float s = 0.f;
        const float* zp = Zp + (size_t)b * (NBLK * 4) * 64 + tid;
        for (int k = 0; k < NBLK * 4; k++) s += zp[(size_t)k * 64];
        Zl[tid] = 1.0f / s;
    }
    __syncthreads();
    const float* sp = Sp + (size_t)b * NBLK * 4096;
    float* mp = M + (size_t)b * 4096;
    for (int idx = tid; idx < 4096; idx += 256) {
        float s = 0.f;
        for (int k = 0; k < NBLK; k++) s += sp[(size_t)k * 4096 + idx];
        mp[idx] = s * Zl[idx & 63];   // idx = c*64+d -> divide by Z[d]
    }
}

// ---------------------------------------------------------------------------
// g projection + channel softmax + att = M @ g_y + residual + leaky_relu.
// gy staged in LDS (runtime-indexed register arrays would go to scratch).
// Softmax 1/Z folded into the final residual add.
// ---------------------------------------------------------------------------
__global__ __launch_bounds__(256) void attn_out(
    const float* __restrict__ x,
    const float* __restrict__ gw, const float* __restrict__ gb,
    const float* __restrict__ M,
    float* __restrict__ out)
{
    __shared__ float gyl[CH][256];   // [chan][thread] : conflict-free
    const int b   = blockIdx.y;
    const int tid = threadIdx.x;
    const int n   = blockIdx.x * 256 + tid;
    const float* xp = x + (size_t)b * CH * HWN + n;
    float xr[CH];
#pragma unroll
    for (int c = 0; c < CH; c++) xr[c] = xp[(size_t)c * HWN];

#pragma unroll 1
    for (int o = 0; o < CH; o++) {
        float g = gb[o];
        const float* w = gw + o * CH;
#pragma unroll
        for (int c = 0; c < CH; c++) g = fmaf(w[c], xr[c], g);
        gyl[o][tid] = g;
    }

    float m = gyl[0][tid];
#pragma unroll 1
    for (int o = 1; o < CH; o++) m = fmaxf(m, gyl[o][tid]);

    float att[CH];
#pragma unroll
    for (int c = 0; c < CH; c++) att[c] = 0.f;
    float zs = 0.f;
    const float* Mb = M + (size_t)b * 4096;
#pragma unroll 1
    for (int d = 0; d < CH; d++) {
        float e = __expf(gyl[d][tid] - m);
        zs += e;
        const float* mc = Mb + d;
#pragma unroll
        for (int c = 0; c < CH; c++) att[c] = fmaf(mc[(size_t)c * CH], e, att[c]);
    }
    const float rz = 1.0f / zs;

    float* op = out + (size_t)b * CH * HWN + n;
#pragma unroll
    for (int c = 0; c < CH; c++) {
        float v = xr[c] + att[c] * rz;
        op[(size_t)c * HWN] = (v >= 0.f) ? v : 0.1f * v;
    }
}

// ---------------------------------------------------------------------------
extern "C" void kernel_launch(void* const* d_in, const int* in_sizes, int n_in,
                              void* d_out, int out_size, void* d_ws, size_t ws_size,
                              hipStream_t stream)
{
    const float* x   = (const float*)d_in[0];
    const float* gw  = (const float*)d_in[1];
    const float* gb  = (const float*)d_in[2];
    const float* thw = (const float*)d_in[3];
    const float* thb = (const float*)d_in[4];
    const float* phw = (const float*)d_in[5];
    const float* phb = (const float*)d_in[6];
    float* out = (float*)d_out;

    char* ws = (char*)d_ws;
    float* Sp = (float*)(ws + SP_OFF);
    float* Zp = (float*)(ws + ZP_OFF);
    float* M  = (float*)(ws + M_OFF);

    dim3 blk(256);
    proj_s<<<dim3(NBLK, BATCH), blk, 0, stream>>>(x, thw, thb, phw, phb, Sp, Zp);
    normalize_S<<<dim3(BATCH), blk, 0, stream>>>(Sp, Zp, M);
    attn_out<<<dim3(HWN / 256, BATCH), blk, 0, stream>>>(x, gw, gb, M, out);
}

// Round 3
// 814.620 us; speedup vs baseline: 1.7373x; 1.7373x over previous
//
#include <hip/hip_runtime.h>
#include <hip/hip_fp16.h>
#include <cstdint>
#include <cstddef>

#define BATCH 16
#define CH 64
#define HWN 65536
#define NBLK 64          // blocks per batch in proj_s (1024 px each)
#define NPAD 136         // ushort row stride for P/E in LDS (272 B: frag reads ~conflict-free)

typedef __attribute__((ext_vector_type(8))) _Float16 half8;
typedef __attribute__((ext_vector_type(4))) float f32x4;

// ---------------- workspace layout (bytes) ----------------
// Sp: [B*NBLK][4096] f32  (split-K partial S)   16 MB
// Zp: [B*NBLK][4][64] f32 (split-K partial Z)    1 MB
// M : [B][64][64] f32     (normalized sim)     256 KB
static const size_t SP_OFF = 0;
static const size_t ZP_OFF = SP_OFF + (size_t)BATCH * NBLK * 4096 * 4;
static const size_t M_OFF  = ZP_OFF + (size_t)BATCH * NBLK * 4 * 64 * 4;

// ---------------------------------------------------------------------------
// Fused MFMA kernel: theta/phi 1x1-conv projections + S-GEMM + Z.
//   T[o,n] = sum_c thw[o,c] x[c,n] + thb[o]; E = exp(T)  (f16 in LDS)
//   P[o,n] = sum_c phw[o,c] x[c,n] + phb[o]              (f16 in LDS)
//   S[c,d] += sum_n P[c,n] E[d,n];  Z[d] += sum_n E[d,n]
// MFMA 16x16x32 f16. A-fragments of row-major [row][k] are b128 reads
// (lane l: row=l%16, k=8*(l>>4)+i). Loading the B-operand with the SAME
// pattern from row-major E[d][n] yields E^T as required (any within-frag
// k-permutation is identical for A and B and cancels in the dot product).
// Split-K over NBLK blocks/batch; deterministic partials, no atomics.
// ---------------------------------------------------------------------------
__global__ __launch_bounds__(256) void proj_s(
    const float* __restrict__ x,
    const float* __restrict__ thw, const float* __restrict__ thb,
    const float* __restrict__ phw, const float* __restrict__ phb,
    float* __restrict__ Sp, float* __restrict__ Zp)
{
    __shared__ ushort El[64 * NPAD];   // 17.4 KB
    __shared__ ushort Pl[64 * NPAD];   // 17.4 KB
    const int b   = blockIdx.y;
    const int blk = blockIdx.x;
    const int tid = threadIdx.x;
    const int wid = tid >> 6;
    const int l   = tid & 63;
    const int lr  = l & 15;            // row-in-tile / col-in-D
    const int lg  = l >> 4;            // k-group / row-group-in-D

    // ---- preload weight A-fragments: Wf[p][ot][g], k = g*32 + lg*8 + i ----
    half8 Wf[2][4][2];
#pragma unroll
    for (int p = 0; p < 2; p++) {
        const float* wsrc = p ? phw : thw;
#pragma unroll
        for (int ot = 0; ot < 4; ot++)
#pragma unroll
            for (int g = 0; g < 2; g++) {
                const float* wp = wsrc + (ot * 16 + lr) * 64 + g * 32 + lg * 8;
                half8 f;
#pragma unroll
                for (int i = 0; i < 8; i++) f[i] = (_Float16)wp[i];
                Wf[p][ot][g] = f;
            }
    }
    // biases for accumulator rows: row = ot*16 + lg*4 + i
    float bT[16], bP[16];
#pragma unroll
    for (int ot = 0; ot < 4; ot++)
#pragma unroll
        for (int i = 0; i < 4; i++) {
            bT[ot * 4 + i] = thb[ot * 16 + lg * 4 + i];
            bP[ot * 4 + i] = phb[ot * 16 + lg * 4 + i];
        }

    f32x4 Sacc[4];
#pragma unroll
    for (int j = 0; j < 4; j++) Sacc[j] = (f32x4){0.f, 0.f, 0.f, 0.f};
    float z[16];
#pragma unroll
    for (int k = 0; k < 16; k++) z[k] = 0.f;

    const float* xb = x + (size_t)b * CH * HWN;

    for (int chk = 0; chk < 8; chk++) {
        const int nb = blk * 1024 + chk * 128;
        // ---- phase A: projections for this wave's 32-px slice ----
#pragma unroll
        for (int nt = 0; nt < 2; nt++) {
            const int ncol = wid * 32 + nt * 16 + lr;   // col within chunk [0,128)
            const float* xp = xb + (nb + ncol);
            half8 xf0, xf1;                              // B-frags straight from global
#pragma unroll
            for (int i = 0; i < 8; i++) xf0[i] = (_Float16)xp[(size_t)(lg * 8 + i) * HWN];
#pragma unroll
            for (int i = 0; i < 8; i++) xf1[i] = (_Float16)xp[(size_t)(32 + lg * 8 + i) * HWN];
#pragma unroll
            for (int ot = 0; ot < 4; ot++) {
                const int off = (ot * 16 + lg * 4) * NPAD + ncol;
                // theta -> E = exp(T), accumulate Z
                f32x4 acc = {bT[ot * 4 + 0], bT[ot * 4 + 1], bT[ot * 4 + 2], bT[ot * 4 + 3]};
                acc = __builtin_amdgcn_mfma_f32_16x16x32_f16(Wf[0][ot][0], xf0, acc, 0, 0, 0);
                acc = __builtin_amdgcn_mfma_f32_16x16x32_f16(Wf[0][ot][1], xf1, acc, 0, 0, 0);
#pragma unroll
                for (int i = 0; i < 4; i++) {
                    float e = __expf(acc[i]);
                    z[ot * 4 + i] += e;
                    El[off + i * NPAD] = __half_as_ushort(__float2half(e));
                }
                // phi -> P
                f32x4 pcc = {bP[ot * 4 + 0], bP[ot * 4 + 1], bP[ot * 4 + 2], bP[ot * 4 + 3]};
                pcc = __builtin_amdgcn_mfma_f32_16x16x32_f16(Wf[1][ot][0], xf0, pcc, 0, 0, 0);
                pcc = __builtin_amdgcn_mfma_f32_16x16x32_f16(Wf[1][ot][1], xf1, pcc, 0, 0, 0);
#pragma unroll
                for (int i = 0; i < 4; i++)
                    Pl[off + i * NPAD] = __half_as_ushort(__float2half(pcc[i]));
            }
        }
        __syncthreads();
        // ---- phase B: S[c-slice, :] += P * E^T over this chunk (K = 128) ----
        const ushort* arow = Pl + (wid * 16 + lr) * NPAD;
#pragma unroll
        for (int g = 0; g < 4; g++) {
            const int coff = g * 32 + lg * 8;
            half8 af = *(const half8*)(arow + coff);
#pragma unroll
            for (int j = 0; j < 4; j++) {
                half8 bf = *(const half8*)(El + (j * 16 + lr) * NPAD + coff);
                Sacc[j] = __builtin_amdgcn_mfma_f32_16x16x32_f16(af, bf, Sacc[j], 0, 0, 0);
            }
        }
        __syncthreads();
    }

    // ---- write S partial: c = wid*16 + lg*4 + i, d = j*16 + lr ----
    float* sp = Sp + (size_t)(b * NBLK + blk) * 4096;
#pragma unroll
    for (int j = 0; j < 4; j++)
#pragma unroll
        for (int i = 0; i < 4; i++)
            sp[(wid * 16 + lg * 4 + i) * 64 + j * 16 + lr] = Sacc[j][i];

    // ---- reduce Z over the 16 lanes of each lg-group, write partials ----
#pragma unroll
    for (int k = 0; k < 16; k++) {
        float v = z[k];
        v += __shfl_xor(v, 1, 64);
        v += __shfl_xor(v, 2, 64);
        v += __shfl_xor(v, 4, 64);
        v += __shfl_xor(v, 8, 64);
        z[k] = v;
    }
    if (lr == 0) {
        float* zp = Zp + ((size_t)(b * NBLK + blk) * 4 + wid) * 64;
#pragma unroll
        for (int t = 0; t < 4; t++)
#pragma unroll
            for (int i = 0; i < 4; i++)
                zp[t * 16 + lg * 4 + i] = z[t * 4 + i];
    }
}

// ---------------------------------------------------------------------------
// Reduce split-K partials; M[b,c,d] = S[b,c,d] / Z[b,d]
// ---------------------------------------------------------------------------
__global__ __launch_bounds__(256) void normalize_S(
    const float* __restrict__ Sp, const float* __restrict__ Zp,
    float* __restrict__ M)
{
    const int b   = blockIdx.x;
    const int tid = threadIdx.x;
    __shared__ float Zl[64];
    if (tid < 64) {
        float s = 0.f;
        const float* zp = Zp + (size_t)b * (NBLK * 4) * 64 + tid;
        for (int k = 0; k < NBLK * 4; k++) s += zp[(size_t)k * 64];
        Zl[tid] = 1.0f / s;
    }
    __syncthreads();
    const float* sp = Sp + (size_t)b * NBLK * 4096;
    float* mp = M + (size_t)b * 4096;
    for (int idx = tid; idx < 4096; idx += 256) {
        float s = 0.f;
        for (int k = 0; k < NBLK; k++) s += sp[(size_t)k * 4096 + idx];
        mp[idx] = s * Zl[idx & 63];   // idx = c*64+d -> divide by Z[d]
    }
}

// ---------------------------------------------------------------------------
// g projection + channel softmax + att = M @ g_y + residual + leaky_relu.
// (unchanged this round; MFMA port next round)
// ---------------------------------------------------------------------------
__global__ __launch_bounds__(256) void attn_out(
    const float* __restrict__ x,
    const float* __restrict__ gw, const float* __restrict__ gb,
    const float* __restrict__ M,
    float* __restrict__ out)
{
    __shared__ float gyl[CH][256];   // [chan][thread] : conflict-free
    const int b   = blockIdx.y;
    const int tid = threadIdx.x;
    const int n   = blockIdx.x * 256 + tid;
    const float* xp = x + (size_t)b * CH * HWN + n;
    float xr[CH];
#pragma unroll
    for (int c = 0; c < CH; c++) xr[c] = xp[(size_t)c * HWN];

#pragma unroll 1
    for (int o = 0; o < CH; o++) {
        float g = gb[o];
        const float* w = gw + o * CH;
#pragma unroll
        for (int c = 0; c < CH; c++) g = fmaf(w[c], xr[c], g);
        gyl[o][tid] = g;
    }

    float m = gyl[0][tid];
#pragma unroll 1
    for (int o = 1; o < CH; o++) m = fmaxf(m, gyl[o][tid]);

    float att[CH];
#pragma unroll
    for (int c = 0; c < CH; c++) att[c] = 0.f;
    float zs = 0.f;
    const float* Mb = M + (size_t)b * 4096;
#pragma unroll 1
    for (int d = 0; d < CH; d++) {
        float e = __expf(gyl[d][tid] - m);
        zs += e;
        const float* mc = Mb + d;
#pragma unroll
        for (int c = 0; c < CH; c++) att[c] = fmaf(mc[(size_t)c * CH], e, att[c]);
    }
    const float rz = 1.0f / zs;

    float* op = out + (size_t)b * CH * HWN + n;
#pragma unroll
    for (int c = 0; c < CH; c++) {
        float v = xr[c] + att[c] * rz;
        op[(size_t)c * HWN] = (v >= 0.f) ? v : 0.1f * v;
    }
}

// ---------------------------------------------------------------------------
extern "C" void kernel_launch(void* const* d_in, const int* in_sizes, int n_in,
                              void* d_out, int out_size, void* d_ws, size_t ws_size,
                              hipStream_t stream)
{
    const float* x   = (const float*)d_in[0];
    const float* gw  = (const float*)d_in[1];
    const float* gb  = (const float*)d_in[2];
    const float* thw = (const float*)d_in[3];
    const float* thb = (const float*)d_in[4];
    const float* phw = (const float*)d_in[5];
    const float* phb = (const float*)d_in[6];
    float* out = (float*)d_out;

    char* ws = (char*)d_ws;
    float* Sp = (float*)(ws + SP_OFF);
    float* Zp = (float*)(ws + ZP_OFF);
    float* M  = (float*)(ws + M_OFF);

    dim3 blk(256);
    proj_s<<<dim3(NBLK, BATCH), blk, 0, stream>>>(x, thw, thb, phw, phb, Sp, Zp);
    normalize_S<<<dim3(BATCH), blk, 0, stream>>>(Sp, Zp, M);
    attn_out<<<dim3(HWN / 256, BATCH), blk, 0, stream>>>(x, gw, gb, M, out);
}

// Round 4
// 391.381 us; speedup vs baseline: 3.6160x; 2.0814x over previous
//
#include <hip/hip_runtime.h>
#include <hip/hip_fp16.h>
#include <cstdint>
#include <cstddef>

#define BATCH 16
#define CH 64
#define HWN 65536
#define NBLK 64          // blocks per batch in proj_s (1024 px each)
#define NPAD 136         // ushort row stride for P/E in LDS (proj_s)
#define DPAD 72          // ushort row stride for e in LDS (attn)

typedef __attribute__((ext_vector_type(8))) _Float16 half8;
typedef __attribute__((ext_vector_type(4))) float f32x4;

// ---------------- workspace layout (bytes) ----------------
static const size_t SP_OFF = 0;
static const size_t ZP_OFF = SP_OFF + (size_t)BATCH * NBLK * 4096 * 4;
static const size_t M_OFF  = ZP_OFF + (size_t)BATCH * NBLK * 4 * 64 * 4;

// ---------------------------------------------------------------------------
// Fused MFMA kernel: theta/phi 1x1-conv projections + S-GEMM + Z.
// (unchanged from R3 — validated)
// ---------------------------------------------------------------------------
__global__ __launch_bounds__(256) void proj_s(
    const float* __restrict__ x,
    const float* __restrict__ thw, const float* __restrict__ thb,
    const float* __restrict__ phw, const float* __restrict__ phb,
    float* __restrict__ Sp, float* __restrict__ Zp)
{
    __shared__ ushort El[64 * NPAD];
    __shared__ ushort Pl[64 * NPAD];
    const int b   = blockIdx.y;
    const int blk = blockIdx.x;
    const int tid = threadIdx.x;
    const int wid = tid >> 6;
    const int l   = tid & 63;
    const int lr  = l & 15;
    const int lg  = l >> 4;

    half8 Wf[2][4][2];
#pragma unroll
    for (int p = 0; p < 2; p++) {
        const float* wsrc = p ? phw : thw;
#pragma unroll
        for (int ot = 0; ot < 4; ot++)
#pragma unroll
            for (int g = 0; g < 2; g++) {
                const float* wp = wsrc + (ot * 16 + lr) * 64 + g * 32 + lg * 8;
                half8 f;
#pragma unroll
                for (int i = 0; i < 8; i++) f[i] = (_Float16)wp[i];
                Wf[p][ot][g] = f;
            }
    }
    float bT[16], bP[16];
#pragma unroll
    for (int ot = 0; ot < 4; ot++)
#pragma unroll
        for (int i = 0; i < 4; i++) {
            bT[ot * 4 + i] = thb[ot * 16 + lg * 4 + i];
            bP[ot * 4 + i] = phb[ot * 16 + lg * 4 + i];
        }

    f32x4 Sacc[4];
#pragma unroll
    for (int j = 0; j < 4; j++) Sacc[j] = (f32x4){0.f, 0.f, 0.f, 0.f};
    float z[16];
#pragma unroll
    for (int k = 0; k < 16; k++) z[k] = 0.f;

    const float* xb = x + (size_t)b * CH * HWN;

    for (int chk = 0; chk < 8; chk++) {
        const int nb = blk * 1024 + chk * 128;
#pragma unroll
        for (int nt = 0; nt < 2; nt++) {
            const int ncol = wid * 32 + nt * 16 + lr;
            const float* xp = xb + (nb + ncol);
            half8 xf0, xf1;
#pragma unroll
            for (int i = 0; i < 8; i++) xf0[i] = (_Float16)xp[(size_t)(lg * 8 + i) * HWN];
#pragma unroll
            for (int i = 0; i < 8; i++) xf1[i] = (_Float16)xp[(size_t)(32 + lg * 8 + i) * HWN];
#pragma unroll
            for (int ot = 0; ot < 4; ot++) {
                const int off = (ot * 16 + lg * 4) * NPAD + ncol;
                f32x4 acc = {bT[ot * 4 + 0], bT[ot * 4 + 1], bT[ot * 4 + 2], bT[ot * 4 + 3]};
                acc = __builtin_amdgcn_mfma_f32_16x16x32_f16(Wf[0][ot][0], xf0, acc, 0, 0, 0);
                acc = __builtin_amdgcn_mfma_f32_16x16x32_f16(Wf[0][ot][1], xf1, acc, 0, 0, 0);
#pragma unroll
                for (int i = 0; i < 4; i++) {
                    float e = __expf(acc[i]);
                    z[ot * 4 + i] += e;
                    El[off + i * NPAD] = __half_as_ushort(__float2half(e));
                }
                f32x4 pcc = {bP[ot * 4 + 0], bP[ot * 4 + 1], bP[ot * 4 + 2], bP[ot * 4 + 3]};
                pcc = __builtin_amdgcn_mfma_f32_16x16x32_f16(Wf[1][ot][0], xf0, pcc, 0, 0, 0);
                pcc = __builtin_amdgcn_mfma_f32_16x16x32_f16(Wf[1][ot][1], xf1, pcc, 0, 0, 0);
#pragma unroll
                for (int i = 0; i < 4; i++)
                    Pl[off + i * NPAD] = __half_as_ushort(__float2half(pcc[i]));
            }
        }
        __syncthreads();
        const ushort* arow = Pl + (wid * 16 + lr) * NPAD;
#pragma unroll
        for (int g = 0; g < 4; g++) {
            const int coff = g * 32 + lg * 8;
            half8 af = *(const half8*)(arow + coff);
#pragma unroll
            for (int j = 0; j < 4; j++) {
                half8 bf = *(const half8*)(El + (j * 16 + lr) * NPAD + coff);
                Sacc[j] = __builtin_amdgcn_mfma_f32_16x16x32_f16(af, bf, Sacc[j], 0, 0, 0);
            }
        }
        __syncthreads();
    }

    float* sp = Sp + (size_t)(b * NBLK + blk) * 4096;
#pragma unroll
    for (int j = 0; j < 4; j++)
#pragma unroll
        for (int i = 0; i < 4; i++)
            sp[(wid * 16 + lg * 4 + i) * 64 + j * 16 + lr] = Sacc[j][i];

#pragma unroll
    for (int k = 0; k < 16; k++) {
        float v = z[k];
        v += __shfl_xor(v, 1, 64);
        v += __shfl_xor(v, 2, 64);
        v += __shfl_xor(v, 4, 64);
        v += __shfl_xor(v, 8, 64);
        z[k] = v;
    }
    if (lr == 0) {
        float* zp = Zp + ((size_t)(b * NBLK + blk) * 4 + wid) * 64;
#pragma unroll
        for (int t = 0; t < 4; t++)
#pragma unroll
            for (int i = 0; i < 4; i++)
                zp[t * 16 + lg * 4 + i] = z[t * 4 + i];
    }
}

// ---------------------------------------------------------------------------
// Reduce split-K partials; M[b,c,d] = S[b,c,d] / Z[b,d]  (unchanged)
// ---------------------------------------------------------------------------
__global__ __launch_bounds__(256) void normalize_S(
    const float* __restrict__ Sp, const float* __restrict__ Zp,
    float* __restrict__ M)
{
    const int b   = blockIdx.x;
    const int tid = threadIdx.x;
    __shared__ float Zl[64];
    if (tid < 64) {
        float s = 0.f;
        const float* zp = Zp + (size_t)b * (NBLK * 4) * 64 + tid;
        for (int k = 0; k < NBLK * 4; k++) s += zp[(size_t)k * 64];
        Zl[tid] = 1.0f / s;
    }
    __syncthreads();
    const float* sp = Sp + (size_t)b * NBLK * 4096;
    float* mp = M + (size_t)b * 4096;
    for (int idx = tid; idx < 4096; idx += 256) {
        float s = 0.f;
        for (int k = 0; k < NBLK; k++) s += sp[(size_t)k * 4096 + idx];
        mp[idx] = s * Zl[idx & 63];
    }
}

// ---------------------------------------------------------------------------
// MFMA attention epilogue: g-projection -> channel softmax -> att = M @ e
// -> (1/Z)*att + x -> leaky_relu.  128 px / block, 4 waves x 32 px.
// Phase A: gy[d,n] via MFMA (A=gw frags, B=x frags); accumulator layout
//   col n = lane&15, row d = (lane>>4)*4 + i  (guide-verified m89/m91).
// Softmax over d: in-thread (4 ot x 4 i) + shfl_xor 16/32 over the lg lanes.
// e=exp(gy-m) stored f16 to LDS [n][d] so phase B's B-frag (col=n, k=d) is a
// contiguous b128 read. Phase B: A = M f16 frags (per-batch, ~0.007 magnitude,
// f16 rounding negligible); 1/Z + residual + lrelu in epilogue.
// ---------------------------------------------------------------------------
__global__ __launch_bounds__(256) void attn_mfma(
    const float* __restrict__ x,
    const float* __restrict__ gw, const float* __restrict__ gb,
    const float* __restrict__ M,
    float* __restrict__ out)
{
    __shared__ ushort El[128 * DPAD];   // 18.4 KB
    const int b   = blockIdx.y;
    const int nb  = blockIdx.x * 128;
    const int tid = threadIdx.x;
    const int wid = tid >> 6;
    const int l   = tid & 63;
    const int lr  = l & 15;
    const int lg  = l >> 4;

    const float* xb = x + (size_t)b * CH * HWN;
    float* outb = out + (size_t)b * CH * HWN;

    // g-weight A-frags + bias
    half8 Gf[4][2];
#pragma unroll
    for (int ot = 0; ot < 4; ot++)
#pragma unroll
        for (int kg = 0; kg < 2; kg++) {
            const float* wp = gw + (ot * 16 + lr) * 64 + kg * 32 + lg * 8;
            half8 f;
#pragma unroll
            for (int i = 0; i < 8; i++) f[i] = (_Float16)wp[i];
            Gf[ot][kg] = f;
        }
    float bG[16];
#pragma unroll
    for (int ot = 0; ot < 4; ot++)
#pragma unroll
        for (int i = 0; i < 4; i++) bG[ot * 4 + i] = gb[ot * 16 + lg * 4 + i];

    // M A-frags (f16)
    half8 Mf[4][2];
    const float* Mb = M + (size_t)b * 4096;
#pragma unroll
    for (int ct = 0; ct < 4; ct++)
#pragma unroll
        for (int kg = 0; kg < 2; kg++) {
            const float* mp = Mb + (ct * 16 + lr) * 64 + kg * 32 + lg * 8;
            half8 f;
#pragma unroll
            for (int i = 0; i < 8; i++) f[i] = (_Float16)mp[i];
            Mf[ct][kg] = f;
        }

    float rz[2];
    // ---- phase A: g-projection + softmax, e -> LDS [n][d] ----
#pragma unroll
    for (int nt = 0; nt < 2; nt++) {
        const int ncol = wid * 32 + nt * 16 + lr;
        const float* xp = xb + nb + ncol;
        half8 xf0, xf1;
#pragma unroll
        for (int i = 0; i < 8; i++) xf0[i] = (_Float16)xp[(size_t)(lg * 8 + i) * HWN];
#pragma unroll
        for (int i = 0; i < 8; i++) xf1[i] = (_Float16)xp[(size_t)(32 + lg * 8 + i) * HWN];

        float gy[4][4];
#pragma unroll
        for (int ot = 0; ot < 4; ot++) {
            f32x4 acc = {bG[ot * 4 + 0], bG[ot * 4 + 1], bG[ot * 4 + 2], bG[ot * 4 + 3]};
            acc = __builtin_amdgcn_mfma_f32_16x16x32_f16(Gf[ot][0], xf0, acc, 0, 0, 0);
            acc = __builtin_amdgcn_mfma_f32_16x16x32_f16(Gf[ot][1], xf1, acc, 0, 0, 0);
#pragma unroll
            for (int i = 0; i < 4; i++) gy[ot][i] = acc[i];
        }
        float m = gy[0][0];
#pragma unroll
        for (int ot = 0; ot < 4; ot++)
#pragma unroll
            for (int i = 0; i < 4; i++) m = fmaxf(m, gy[ot][i]);
        m = fmaxf(m, __shfl_xor(m, 16, 64));
        m = fmaxf(m, __shfl_xor(m, 32, 64));

        float zs = 0.f;
        ushort* erow = El + ncol * DPAD;
#pragma unroll
        for (int ot = 0; ot < 4; ot++) {
            float e0 = __expf(gy[ot][0] - m);
            float e1 = __expf(gy[ot][1] - m);
            float e2 = __expf(gy[ot][2] - m);
            float e3 = __expf(gy[ot][3] - m);
            zs += e0 + e1 + e2 + e3;
            uint2 pk;
            pk.x = (uint)__half_as_ushort(__float2half(e0)) |
                   ((uint)__half_as_ushort(__float2half(e1)) << 16);
            pk.y = (uint)__half_as_ushort(__float2half(e2)) |
                   ((uint)__half_as_ushort(__float2half(e3)) << 16);
            *(uint2*)(erow + ot * 16 + lg * 4) = pk;   // 8B aligned (144|row, 8|off)
        }
        zs += __shfl_xor(zs, 16, 64);
        zs += __shfl_xor(zs, 32, 64);
        rz[nt] = 1.0f / zs;
    }
    __syncthreads();

    // ---- phase B: att = M @ e, scale 1/Z, residual, lrelu, store ----
#pragma unroll
    for (int nt = 0; nt < 2; nt++) {
        const int ncol = wid * 32 + nt * 16 + lr;
        const ushort* brow = El + ncol * DPAD;
        half8 bf0 = *(const half8*)(brow + lg * 8);        // k = d in [lg*8, lg*8+8)
        half8 bf1 = *(const half8*)(brow + 32 + lg * 8);   // k = d in [32+lg*8, ...)
        const float sc = rz[nt];
#pragma unroll
        for (int ct = 0; ct < 4; ct++) {
            f32x4 acc = {0.f, 0.f, 0.f, 0.f};
            acc = __builtin_amdgcn_mfma_f32_16x16x32_f16(Mf[ct][0], bf0, acc, 0, 0, 0);
            acc = __builtin_amdgcn_mfma_f32_16x16x32_f16(Mf[ct][1], bf1, acc, 0, 0, 0);
#pragma unroll
            for (int i = 0; i < 4; i++) {
                const size_t off = (size_t)(ct * 16 + lg * 4 + i) * HWN + nb + ncol;
                float v = xb[off] + acc[i] * sc;
                outb[off] = (v >= 0.f) ? v : 0.1f * v;
            }
        }
    }
}

// ---------------------------------------------------------------------------
extern "C" void kernel_launch(void* const* d_in, const int* in_sizes, int n_in,
                              void* d_out, int out_size, void* d_ws, size_t ws_size,
                              hipStream_t stream)
{
    const float* x   = (const float*)d_in[0];
    const float* gw  = (const float*)d_in[1];
    const float* gb  = (const float*)d_in[2];
    const float* thw = (const float*)d_in[3];
    const float* thb = (const float*)d_in[4];
    const float* phw = (const float*)d_in[5];
    const float* phb = (const float*)d_in[6];
    float* out = (float*)d_out;

    char* ws = (char*)d_ws;
    float* Sp = (float*)(ws + SP_OFF);
    float* Zp = (float*)(ws + ZP_OFF);
    float* M  = (float*)(ws + M_OFF);

    dim3 blk(256);
    proj_s<<<dim3(NBLK, BATCH), blk, 0, stream>>>(x, thw, thb, phw, phb, Sp, Zp);
    normalize_S<<<dim3(BATCH), blk, 0, stream>>>(Sp, Zp, M);
    attn_mfma<<<dim3(HWN / 128, BATCH), blk, 0, stream>>>(x, gw, gb, M, out);
}

// Round 5
// 300.038 us; speedup vs baseline: 4.7169x; 1.3044x over previous
//
#include <hip/hip_runtime.h>
#include <hip/hip_fp16.h>
#include <cstdint>
#include <cstddef>

#define BATCH 16
#define CH 64
#define HWN 65536
#define NBLK 64          // blocks per batch in proj_s (1024 px each)
#define NPAD 136         // ushort row stride for P/E in LDS (proj_s)
#define DPAD 72          // ushort row stride for e in LDS (attn)
#define ACHUNK 8         // chunks (128 px) per attn block -> 1024 px/block

typedef __attribute__((ext_vector_type(8))) _Float16 half8;
typedef __attribute__((ext_vector_type(4))) float f32x4;

// ---------------- workspace layout (bytes) ----------------
static const size_t SP_OFF = 0;
static const size_t ZP_OFF = SP_OFF + (size_t)BATCH * NBLK * 4096 * 4;
static const size_t M_OFF  = ZP_OFF + (size_t)BATCH * NBLK * 4 * 64 * 4;

__device__ __forceinline__ half8 load_frag_f32(const float* p) {
    const float4 w0 = *(const float4*)p;
    const float4 w1 = *(const float4*)(p + 4);
    half8 f;
    f[0] = (_Float16)w0.x; f[1] = (_Float16)w0.y;
    f[2] = (_Float16)w0.z; f[3] = (_Float16)w0.w;
    f[4] = (_Float16)w1.x; f[5] = (_Float16)w1.y;
    f[6] = (_Float16)w1.z; f[7] = (_Float16)w1.w;
    return f;
}

// ---------------------------------------------------------------------------
// Fused MFMA kernel: theta/phi 1x1-conv projections + S-GEMM + Z.
// (unchanged from R3 — validated)
// ---------------------------------------------------------------------------
__global__ __launch_bounds__(256) void proj_s(
    const float* __restrict__ x,
    const float* __restrict__ thw, const float* __restrict__ thb,
    const float* __restrict__ phw, const float* __restrict__ phb,
    float* __restrict__ Sp, float* __restrict__ Zp)
{
    __shared__ ushort El[64 * NPAD];
    __shared__ ushort Pl[64 * NPAD];
    const int b   = blockIdx.y;
    const int blk = blockIdx.x;
    const int tid = threadIdx.x;
    const int wid = tid >> 6;
    const int l   = tid & 63;
    const int lr  = l & 15;
    const int lg  = l >> 4;

    half8 Wf[2][4][2];
#pragma unroll
    for (int p = 0; p < 2; p++) {
        const float* wsrc = p ? phw : thw;
#pragma unroll
        for (int ot = 0; ot < 4; ot++)
#pragma unroll
            for (int g = 0; g < 2; g++)
                Wf[p][ot][g] = load_frag_f32(wsrc + (ot * 16 + lr) * 64 + g * 32 + lg * 8);
    }
    float bT[16], bP[16];
#pragma unroll
    for (int ot = 0; ot < 4; ot++)
#pragma unroll
        for (int i = 0; i < 4; i++) {
            bT[ot * 4 + i] = thb[ot * 16 + lg * 4 + i];
            bP[ot * 4 + i] = phb[ot * 16 + lg * 4 + i];
        }

    f32x4 Sacc[4];
#pragma unroll
    for (int j = 0; j < 4; j++) Sacc[j] = (f32x4){0.f, 0.f, 0.f, 0.f};
    float z[16];
#pragma unroll
    for (int k = 0; k < 16; k++) z[k] = 0.f;

    const float* xb = x + (size_t)b * CH * HWN;

    for (int chk = 0; chk < 8; chk++) {
        const int nb = blk * 1024 + chk * 128;
#pragma unroll
        for (int nt = 0; nt < 2; nt++) {
            const int ncol = wid * 32 + nt * 16 + lr;
            const float* xp = xb + (nb + ncol);
            half8 xf0, xf1;
#pragma unroll
            for (int i = 0; i < 8; i++) xf0[i] = (_Float16)xp[(size_t)(lg * 8 + i) * HWN];
#pragma unroll
            for (int i = 0; i < 8; i++) xf1[i] = (_Float16)xp[(size_t)(32 + lg * 8 + i) * HWN];
#pragma unroll
            for (int ot = 0; ot < 4; ot++) {
                const int off = (ot * 16 + lg * 4) * NPAD + ncol;
                f32x4 acc = {bT[ot * 4 + 0], bT[ot * 4 + 1], bT[ot * 4 + 2], bT[ot * 4 + 3]};
                acc = __builtin_amdgcn_mfma_f32_16x16x32_f16(Wf[0][ot][0], xf0, acc, 0, 0, 0);
                acc = __builtin_amdgcn_mfma_f32_16x16x32_f16(Wf[0][ot][1], xf1, acc, 0, 0, 0);
#pragma unroll
                for (int i = 0; i < 4; i++) {
                    float e = __expf(acc[i]);
                    z[ot * 4 + i] += e;
                    El[off + i * NPAD] = __half_as_ushort(__float2half(e));
                }
                f32x4 pcc = {bP[ot * 4 + 0], bP[ot * 4 + 1], bP[ot * 4 + 2], bP[ot * 4 + 3]};
                pcc = __builtin_amdgcn_mfma_f32_16x16x32_f16(Wf[1][ot][0], xf0, pcc, 0, 0, 0);
                pcc = __builtin_amdgcn_mfma_f32_16x16x32_f16(Wf[1][ot][1], xf1, pcc, 0, 0, 0);
#pragma unroll
                for (int i = 0; i < 4; i++)
                    Pl[off + i * NPAD] = __half_as_ushort(__float2half(pcc[i]));
            }
        }
        __syncthreads();
        const ushort* arow = Pl + (wid * 16 + lr) * NPAD;
#pragma unroll
        for (int g = 0; g < 4; g++) {
            const int coff = g * 32 + lg * 8;
            half8 af = *(const half8*)(arow + coff);
#pragma unroll
            for (int j = 0; j < 4; j++) {
                half8 bf = *(const half8*)(El + (j * 16 + lr) * NPAD + coff);
                Sacc[j] = __builtin_amdgcn_mfma_f32_16x16x32_f16(af, bf, Sacc[j], 0, 0, 0);
            }
        }
        __syncthreads();
    }

    float* sp = Sp + (size_t)(b * NBLK + blk) * 4096;
#pragma unroll
    for (int j = 0; j < 4; j++)
#pragma unroll
        for (int i = 0; i < 4; i++)
            sp[(wid * 16 + lg * 4 + i) * 64 + j * 16 + lr] = Sacc[j][i];

#pragma unroll
    for (int k = 0; k < 16; k++) {
        float v = z[k];
        v += __shfl_xor(v, 1, 64);
        v += __shfl_xor(v, 2, 64);
        v += __shfl_xor(v, 4, 64);
        v += __shfl_xor(v, 8, 64);
        z[k] = v;
    }
    if (lr == 0) {
        float* zp = Zp + ((size_t)(b * NBLK + blk) * 4 + wid) * 64;
#pragma unroll
        for (int t = 0; t < 4; t++)
#pragma unroll
            for (int i = 0; i < 4; i++)
                zp[t * 16 + lg * 4 + i] = z[t * 4 + i];
    }
}

// ---------------------------------------------------------------------------
// Reduce split-K partials; M[b,c,d] = S[b,c,d] / Z[b,d]  (unchanged)
// ---------------------------------------------------------------------------
__global__ __launch_bounds__(256) void normalize_S(
    const float* __restrict__ Sp, const float* __restrict__ Zp,
    float* __restrict__ M)
{
    const int b   = blockIdx.x;
    const int tid = threadIdx.x;
    __shared__ float Zl[64];
    if (tid < 64) {
        float s = 0.f;
        const float* zp = Zp + (size_t)b * (NBLK * 4) * 64 + tid;
        for (int k = 0; k < NBLK * 4; k++) s += zp[(size_t)k * 64];
        Zl[tid] = 1.0f / s;
    }
    __syncthreads();
    const float* sp = Sp + (size_t)b * NBLK * 4096;
    float* mp = M + (size_t)b * 4096;
    for (int idx = tid; idx < 4096; idx += 256) {
        float s = 0.f;
        for (int k = 0; k < NBLK; k++) s += sp[(size_t)k * 4096 + idx];
        mp[idx] = s * Zl[idx & 63];
    }
}

// ---------------------------------------------------------------------------
// MFMA attention epilogue, chunked: each block keeps gw/M fragments resident
// and processes ACHUNK x 128 px, amortizing the per-block preload 8x.
// Phase A: gy via MFMA -> channel softmax -> e (f16) in LDS [n][d].
// Phase B: att = M @ e via MFMA; (1/Z)*att + x; leaky_relu; store.
// ---------------------------------------------------------------------------
__global__ __launch_bounds__(256) void attn_mfma(
    const float* __restrict__ x,
    const float* __restrict__ gw, const float* __restrict__ gb,
    const float* __restrict__ M,
    float* __restrict__ out)
{
    __shared__ ushort El[128 * DPAD];   // 18.4 KB
    const int b   = blockIdx.y;
    const int tid = threadIdx.x;
    const int wid = tid >> 6;
    const int l   = tid & 63;
    const int lr  = l & 15;
    const int lg  = l >> 4;

    const float* xb = x + (size_t)b * CH * HWN;
    float* outb = out + (size_t)b * CH * HWN;

    // g-weight A-frags + bias (resident across chunks)
    half8 Gf[4][2];
#pragma unroll
    for (int ot = 0; ot < 4; ot++)
#pragma unroll
        for (int kg = 0; kg < 2; kg++)
            Gf[ot][kg] = load_frag_f32(gw + (ot * 16 + lr) * 64 + kg * 32 + lg * 8);
    float bG[16];
#pragma unroll
    for (int ot = 0; ot < 4; ot++)
#pragma unroll
        for (int i = 0; i < 4; i++) bG[ot * 4 + i] = gb[ot * 16 + lg * 4 + i];

    // M A-frags (f16; |M| ~ 1e-2, rounding negligible)
    half8 Mf[4][2];
    const float* Mb = M + (size_t)b * 4096;
#pragma unroll
    for (int ct = 0; ct < 4; ct++)
#pragma unroll
        for (int kg = 0; kg < 2; kg++)
            Mf[ct][kg] = load_frag_f32(Mb + (ct * 16 + lr) * 64 + kg * 32 + lg * 8);

    for (int chk = 0; chk < ACHUNK; chk++) {
        const int nb = blockIdx.x * (128 * ACHUNK) + chk * 128;
        float rz[2];

        // ---- phase A: g-projection + softmax, e -> LDS [n][d] ----
#pragma unroll
        for (int nt = 0; nt < 2; nt++) {
            const int ncol = wid * 32 + nt * 16 + lr;
            const float* xp = xb + nb + ncol;
            half8 xf0, xf1;
#pragma unroll
            for (int i = 0; i < 8; i++) xf0[i] = (_Float16)xp[(size_t)(lg * 8 + i) * HWN];
#pragma unroll
            for (int i = 0; i < 8; i++) xf1[i] = (_Float16)xp[(size_t)(32 + lg * 8 + i) * HWN];

            float gy[4][4];
#pragma unroll
            for (int ot = 0; ot < 4; ot++) {
                f32x4 acc = {bG[ot * 4 + 0], bG[ot * 4 + 1], bG[ot * 4 + 2], bG[ot * 4 + 3]};
                acc = __builtin_amdgcn_mfma_f32_16x16x32_f16(Gf[ot][0], xf0, acc, 0, 0, 0);
                acc = __builtin_amdgcn_mfma_f32_16x16x32_f16(Gf[ot][1], xf1, acc, 0, 0, 0);
#pragma unroll
                for (int i = 0; i < 4; i++) gy[ot][i] = acc[i];
            }
            float m = gy[0][0];
#pragma unroll
            for (int ot = 0; ot < 4; ot++)
#pragma unroll
                for (int i = 0; i < 4; i++) m = fmaxf(m, gy[ot][i]);
            m = fmaxf(m, __shfl_xor(m, 16, 64));
            m = fmaxf(m, __shfl_xor(m, 32, 64));

            float zs = 0.f;
            ushort* erow = El + ncol * DPAD;
#pragma unroll
            for (int ot = 0; ot < 4; ot++) {
                float e0 = __expf(gy[ot][0] - m);
                float e1 = __expf(gy[ot][1] - m);
                float e2 = __expf(gy[ot][2] - m);
                float e3 = __expf(gy[ot][3] - m);
                zs += e0 + e1 + e2 + e3;
                uint2 pk;
                pk.x = (uint)__half_as_ushort(__float2half(e0)) |
                       ((uint)__half_as_ushort(__float2half(e1)) << 16);
                pk.y = (uint)__half_as_ushort(__float2half(e2)) |
                       ((uint)__half_as_ushort(__float2half(e3)) << 16);
                *(uint2*)(erow + ot * 16 + lg * 4) = pk;
            }
            zs += __shfl_xor(zs, 16, 64);
            zs += __shfl_xor(zs, 32, 64);
            rz[nt] = 1.0f / zs;
        }
        __syncthreads();

        // ---- phase B: att = M @ e, scale 1/Z, residual, lrelu, store ----
#pragma unroll
        for (int nt = 0; nt < 2; nt++) {
            const int ncol = wid * 32 + nt * 16 + lr;
            const ushort* brow = El + ncol * DPAD;
            half8 bf0 = *(const half8*)(brow + lg * 8);
            half8 bf1 = *(const half8*)(brow + 32 + lg * 8);
            const float sc = rz[nt];
#pragma unroll
            for (int ct = 0; ct < 4; ct++) {
                f32x4 acc = {0.f, 0.f, 0.f, 0.f};
                acc = __builtin_amdgcn_mfma_f32_16x16x32_f16(Mf[ct][0], bf0, acc, 0, 0, 0);
                acc = __builtin_amdgcn_mfma_f32_16x16x32_f16(Mf[ct][1], bf1, acc, 0, 0, 0);
#pragma unroll
                for (int i = 0; i < 4; i++) {
                    const size_t off = (size_t)(ct * 16 + lg * 4 + i) * HWN + nb + ncol;
                    float v = xb[off] + acc[i] * sc;
                    outb[off] = (v >= 0.f) ? v : 0.1f * v;
                }
            }
        }
        __syncthreads();
    }
}

// ---------------------------------------------------------------------------
extern "C" void kernel_launch(void* const* d_in, const int* in_sizes, int n_in,
                              void* d_out, int out_size, void* d_ws, size_t ws_size,
                              hipStream_t stream)
{
    const float* x   = (const float*)d_in[0];
    const float* gw  = (const float*)d_in[1];
    const float* gb  = (const float*)d_in[2];
    const float* thw = (const float*)d_in[3];
    const float* thb = (const float*)d_in[4];
    const float* phw = (const float*)d_in[5];
    const float* phb = (const float*)d_in[6];
    float* out = (float*)d_out;

    char* ws = (char*)d_ws;
    float* Sp = (float*)(ws + SP_OFF);
    float* Zp = (float*)(ws + ZP_OFF);
    float* M  = (float*)(ws + M_OFF);

    dim3 blk(256);
    proj_s<<<dim3(NBLK, BATCH), blk, 0, stream>>>(x, thw, thb, phw, phb, Sp, Zp);
    normalize_S<<<dim3(BATCH), blk, 0, stream>>>(Sp, Zp, M);
    attn_mfma<<<dim3(HWN / (128 * ACHUNK), BATCH), blk, 0, stream>>>(x, gw, gb, M, out);
}

// Round 7
// 289.854 us; speedup vs baseline: 4.8826x; 1.0351x over previous
//
#include <hip/hip_runtime.h>
#include <hip/hip_fp16.h>
#include <cstdint>
#include <cstddef>

#define BATCH 16
#define CH 64
#define HWN 65536
#define NBLK 64          // blocks per batch in proj_s (1024 px each)
#define NPAD 136         // ushort row stride for P/E in LDS (proj_s)
#define DPAD 72          // ushort row stride for e in LDS (attn)
#define TPAD 68          // f32 row stride for attn transpose buffer
#define ACHUNK 8         // chunks (128 px) per attn block -> 1024 px/block

typedef __attribute__((ext_vector_type(8))) _Float16 half8;
typedef __attribute__((ext_vector_type(4))) float f32x4;

// ---------------- workspace layout (bytes) ----------------
static const size_t SP_OFF = 0;
static const size_t ZP_OFF = SP_OFF + (size_t)BATCH * NBLK * 4096 * 4;
static const size_t M_OFF  = ZP_OFF + (size_t)BATCH * NBLK * 4 * 64 * 4;

__device__ __forceinline__ half8 load_frag_f32(const float* p) {
    const float4 w0 = *(const float4*)p;
    const float4 w1 = *(const float4*)(p + 4);
    half8 f;
    f[0] = (_Float16)w0.x; f[1] = (_Float16)w0.y;
    f[2] = (_Float16)w0.z; f[3] = (_Float16)w0.w;
    f[4] = (_Float16)w1.x; f[5] = (_Float16)w1.y;
    f[6] = (_Float16)w1.z; f[7] = (_Float16)w1.w;
    return f;
}

// ---------------------------------------------------------------------------
// Fused MFMA kernel: theta/phi 1x1-conv projections + S-GEMM + Z.
// (unchanged — validated R3-R5)
// ---------------------------------------------------------------------------
__global__ __launch_bounds__(256) void proj_s(
    const float* __restrict__ x,
    const float* __restrict__ thw, const float* __restrict__ thb,
    const float* __restrict__ phw, const float* __restrict__ phb,
    float* __restrict__ Sp, float* __restrict__ Zp)
{
    __shared__ ushort El[64 * NPAD];
    __shared__ ushort Pl[64 * NPAD];
    const int b   = blockIdx.y;
    const int blk = blockIdx.x;
    const int tid = threadIdx.x;
    const int wid = tid >> 6;
    const int l   = tid & 63;
    const int lr  = l & 15;
    const int lg  = l >> 4;

    half8 Wf[2][4][2];
#pragma unroll
    for (int p = 0; p < 2; p++) {
        const float* wsrc = p ? phw : thw;
#pragma unroll
        for (int ot = 0; ot < 4; ot++)
#pragma unroll
            for (int g = 0; g < 2; g++)
                Wf[p][ot][g] = load_frag_f32(wsrc + (ot * 16 + lr) * 64 + g * 32 + lg * 8);
    }
    float bT[16], bP[16];
#pragma unroll
    for (int ot = 0; ot < 4; ot++)
#pragma unroll
        for (int i = 0; i < 4; i++) {
            bT[ot * 4 + i] = thb[ot * 16 + lg * 4 + i];
            bP[ot * 4 + i] = phb[ot * 16 + lg * 4 + i];
        }

    f32x4 Sacc[4];
#pragma unroll
    for (int j = 0; j < 4; j++) Sacc[j] = (f32x4){0.f, 0.f, 0.f, 0.f};
    float z[16];
#pragma unroll
    for (int k = 0; k < 16; k++) z[k] = 0.f;

    const float* xb = x + (size_t)b * CH * HWN;

    for (int chk = 0; chk < 8; chk++) {
        const int nb = blk * 1024 + chk * 128;
#pragma unroll
        for (int nt = 0; nt < 2; nt++) {
            const int ncol = wid * 32 + nt * 16 + lr;
            const float* xp = xb + (nb + ncol);
            half8 xf0, xf1;
#pragma unroll
            for (int i = 0; i < 8; i++) xf0[i] = (_Float16)xp[(size_t)(lg * 8 + i) * HWN];
#pragma unroll
            for (int i = 0; i < 8; i++) xf1[i] = (_Float16)xp[(size_t)(32 + lg * 8 + i) * HWN];
#pragma unroll
            for (int ot = 0; ot < 4; ot++) {
                const int off = (ot * 16 + lg * 4) * NPAD + ncol;
                f32x4 acc = {bT[ot * 4 + 0], bT[ot * 4 + 1], bT[ot * 4 + 2], bT[ot * 4 + 3]};
                acc = __builtin_amdgcn_mfma_f32_16x16x32_f16(Wf[0][ot][0], xf0, acc, 0, 0, 0);
                acc = __builtin_amdgcn_mfma_f32_16x16x32_f16(Wf[0][ot][1], xf1, acc, 0, 0, 0);
#pragma unroll
                for (int i = 0; i < 4; i++) {
                    float e = __expf(acc[i]);
                    z[ot * 4 + i] += e;
                    El[off + i * NPAD] = __half_as_ushort(__float2half(e));
                }
                f32x4 pcc = {bP[ot * 4 + 0], bP[ot * 4 + 1], bP[ot * 4 + 2], bP[ot * 4 + 3]};
                pcc = __builtin_amdgcn_mfma_f32_16x16x32_f16(Wf[1][ot][0], xf0, pcc, 0, 0, 0);
                pcc = __builtin_amdgcn_mfma_f32_16x16x32_f16(Wf[1][ot][1], xf1, pcc, 0, 0, 0);
#pragma unroll
                for (int i = 0; i < 4; i++)
                    Pl[off + i * NPAD] = __half_as_ushort(__float2half(pcc[i]));
            }
        }
        __syncthreads();
        const ushort* arow = Pl + (wid * 16 + lr) * NPAD;
#pragma unroll
        for (int g = 0; g < 4; g++) {
            const int coff = g * 32 + lg * 8;
            half8 af = *(const half8*)(arow + coff);
#pragma unroll
            for (int j = 0; j < 4; j++) {
                half8 bf = *(const half8*)(El + (j * 16 + lr) * NPAD + coff);
                Sacc[j] = __builtin_amdgcn_mfma_f32_16x16x32_f16(af, bf, Sacc[j], 0, 0, 0);
            }
        }
        __syncthreads();
    }

    float* sp = Sp + (size_t)(b * NBLK + blk) * 4096;
#pragma unroll
    for (int j = 0; j < 4; j++)
#pragma unroll
        for (int i = 0; i < 4; i++)
            sp[(wid * 16 + lg * 4 + i) * 64 + j * 16 + lr] = Sacc[j][i];

#pragma unroll
    for (int k = 0; k < 16; k++) {
        float v = z[k];
        v += __shfl_xor(v, 1, 64);
        v += __shfl_xor(v, 2, 64);
        v += __shfl_xor(v, 4, 64);
        v += __shfl_xor(v, 8, 64);
        z[k] = v;
    }
    if (lr == 0) {
        float* zp = Zp + ((size_t)(b * NBLK + blk) * 4 + wid) * 64;
#pragma unroll
        for (int t = 0; t < 4; t++)
#pragma unroll
            for (int i = 0; i < 4; i++)
                zp[t * 16 + lg * 4 + i] = z[t * 4 + i];
    }
}

// ---------------------------------------------------------------------------
// Reduce split-K partials; M[b,c,d] = S[b,c,d] / Z[b,d]
// Grid widened 16 -> 128 blocks (8 cell-slices per batch).
// ---------------------------------------------------------------------------
__global__ __launch_bounds__(256) void normalize_S(
    const float* __restrict__ Sp, const float* __restrict__ Zp,
    float* __restrict__ M)
{
    const int b   = blockIdx.y;
    const int sl  = blockIdx.x;     // 8 slices of 512 cells
    const int tid = threadIdx.x;
    __shared__ float Zl[64];
    if (tid < 64) {
        float s = 0.f;
        const float* zp = Zp + (size_t)b * (NBLK * 4) * 64 + tid;
        for (int k = 0; k < NBLK * 4; k++) s += zp[(size_t)k * 64];
        Zl[tid] = 1.0f / s;
    }
    __syncthreads();
    const float* sp = Sp + (size_t)b * NBLK * 4096;
    float* mp = M + (size_t)b * 4096;
#pragma unroll
    for (int h = 0; h < 2; h++) {
        const int idx = sl * 512 + h * 256 + tid;
        float s = 0.f;
        for (int k = 0; k < NBLK; k++) s += sp[(size_t)k * 4096 + idx];
        mp[idx] = s * Zl[idx & 63];
    }
}

// ---------------------------------------------------------------------------
// MFMA attention epilogue, chunked, with LDS-transposed float4 store path.
// Per chunk (128 px, two 64-px halves):
//   A : gy via MFMA -> softmax -> e (f16) in El[px][ch]  (wave-private rows)
//   B : att = M @ e via MFMA; acc*(1/Z) -> Tl[ch][px] (f32, b32 writes ~2-way)
//   E : float4 {Tl read, x read, +, lrelu, store} — 256B contiguous segments
// El (18.4 KB) and Tl (17.4 KB) disjoint; barriers protect Tl reuse.
// ---------------------------------------------------------------------------
__global__ __launch_bounds__(256) void attn_mfma(
    const float* __restrict__ x,
    const float* __restrict__ gw, const float* __restrict__ gb,
    const float* __restrict__ M,
    float* __restrict__ out)
{
    __shared__ __align__(16) ushort El[128 * DPAD];   // 18.4 KB
    __shared__ __align__(16) float  Tl[64 * TPAD];    // 17.4 KB
    const int b   = blockIdx.y;
    const int tid = threadIdx.x;
    const int wid = tid >> 6;
    const int l   = tid & 63;
    const int lr  = l & 15;
    const int lg  = l >> 4;

    const float* xb = x + (size_t)b * CH * HWN;
    float* outb = out + (size_t)b * CH * HWN;

    // g-weight A-frags + bias (resident across chunks)
    half8 Gf[4][2];
#pragma unroll
    for (int ot = 0; ot < 4; ot++)
#pragma unroll
        for (int kg = 0; kg < 2; kg++)
            Gf[ot][kg] = load_frag_f32(gw + (ot * 16 + lr) * 64 + kg * 32 + lg * 8);
    float bG[16];
#pragma unroll
    for (int ot = 0; ot < 4; ot++)
#pragma unroll
        for (int i = 0; i < 4; i++) bG[ot * 4 + i] = gb[ot * 16 + lg * 4 + i];

    // M A-frags (f16; |M| ~ 1e-2, rounding negligible)
    half8 Mf[4][2];
    const float* Mb = M + (size_t)b * 4096;
#pragma unroll
    for (int ct = 0; ct < 4; ct++)
#pragma unroll
        for (int kg = 0; kg < 2; kg++)
            Mf[ct][kg] = load_frag_f32(Mb + (ct * 16 + lr) * 64 + kg * 32 + lg * 8);

    for (int chk = 0; chk < ACHUNK; chk++) {
        const int nb = blockIdx.x * (128 * ACHUNK) + chk * 128;
        float rz[2];

        // ---- phase A: g-projection + softmax, e -> El[px][ch] ----
#pragma unroll
        for (int nt = 0; nt < 2; nt++) {
            const int ncol = nt * 64 + wid * 16 + lr;   // px within chunk
            const float* xp = xb + nb + ncol;
            half8 xf0, xf1;
#pragma unroll
            for (int i = 0; i < 8; i++) xf0[i] = (_Float16)xp[(size_t)(lg * 8 + i) * HWN];
#pragma unroll
            for (int i = 0; i < 8; i++) xf1[i] = (_Float16)xp[(size_t)(32 + lg * 8 + i) * HWN];

            float gy[4][4];
#pragma unroll
            for (int ot = 0; ot < 4; ot++) {
                f32x4 acc = {bG[ot * 4 + 0], bG[ot * 4 + 1], bG[ot * 4 + 2], bG[ot * 4 + 3]};
                acc = __builtin_amdgcn_mfma_f32_16x16x32_f16(Gf[ot][0], xf0, acc, 0, 0, 0);
                acc = __builtin_amdgcn_mfma_f32_16x16x32_f16(Gf[ot][1], xf1, acc, 0, 0, 0);
#pragma unroll
                for (int i = 0; i < 4; i++) gy[ot][i] = acc[i];
            }
            float m = gy[0][0];
#pragma unroll
            for (int ot = 0; ot < 4; ot++)
#pragma unroll
                for (int i = 0; i < 4; i++) m = fmaxf(m, gy[ot][i]);
            m = fmaxf(m, __shfl_xor(m, 16, 64));
            m = fmaxf(m, __shfl_xor(m, 32, 64));

            float zs = 0.f;
            ushort* erow = El + ncol * DPAD;
#pragma unroll
            for (int ot = 0; ot < 4; ot++) {
                float e0 = __expf(gy[ot][0] - m);
                float e1 = __expf(gy[ot][1] - m);
                float e2 = __expf(gy[ot][2] - m);
                float e3 = __expf(gy[ot][3] - m);
                zs += e0 + e1 + e2 + e3;
                uint2 pk;
                pk.x = (uint)__half_as_ushort(__float2half(e0)) |
                       ((uint)__half_as_ushort(__float2half(e1)) << 16);
                pk.y = (uint)__half_as_ushort(__float2half(e2)) |
                       ((uint)__half_as_ushort(__float2half(e3)) << 16);
                *(uint2*)(erow + ot * 16 + lg * 4) = pk;
            }
            zs += __shfl_xor(zs, 16, 64);
            zs += __shfl_xor(zs, 32, 64);
            rz[nt] = 1.0f / zs;
        }

        // ---- phase B + epilogue, per 64-px half ----
#pragma unroll
        for (int nt = 0; nt < 2; nt++) {
            const int ncol = nt * 64 + wid * 16 + lr;
            const ushort* brow = El + ncol * DPAD;      // wave-private row
            half8 bf0 = *(const half8*)(brow + lg * 8);
            half8 bf1 = *(const half8*)(brow + 32 + lg * 8);
            __syncthreads();   // prior Tl readers (prev half / prev chunk) done
            const float sc = rz[nt];
#pragma unroll
            for (int ct = 0; ct < 4; ct++) {
                f32x4 acc = {0.f, 0.f, 0.f, 0.f};
                acc = __builtin_amdgcn_mfma_f32_16x16x32_f16(Mf[ct][0], bf0, acc, 0, 0, 0);
                acc = __builtin_amdgcn_mfma_f32_16x16x32_f16(Mf[ct][1], bf1, acc, 0, 0, 0);
#pragma unroll
                for (int i = 0; i < 4; i++)
                    Tl[(ct * 16 + lg * 4 + i) * TPAD + wid * 16 + lr] = acc[i] * sc;
            }
            __syncthreads();   // Tl fully written
            // epilogue: 64 ch x 64 px half, float4 per lane, 256B segments
#pragma unroll
            for (int it = 0; it < 4; it++) {
                const int ch = (tid >> 4) + it * 16;
                const int p  = (tid & 15) * 4;
                const float4 a = *(const float4*)&Tl[ch * TPAD + p];
                const size_t go = (size_t)ch * HWN + nb + nt * 64 + p;
                const float4 xv = *(const float4*)(xb + go);
                float4 o;
                float v0 = xv.x + a.x, v1 = xv.y + a.y, v2 = xv.z + a.z, v3 = xv.w + a.w;
                o.x = (v0 >= 0.f) ? v0 : 0.1f * v0;
                o.y = (v1 >= 0.f) ? v1 : 0.1f * v1;
                o.z = (v2 >= 0.f) ? v2 : 0.1f * v2;
                o.w = (v3 >= 0.f) ? v3 : 0.1f * v3;
                *(float4*)(outb + go) = o;
            }
        }
    }
}

// ---------------------------------------------------------------------------
extern "C" void kernel_launch(void* const* d_in, const int* in_sizes, int n_in,
                              void* d_out, int out_size, void* d_ws, size_t ws_size,
                              hipStream_t stream)
{
    const float* x   = (const float*)d_in[0];
    const float* gw  = (const float*)d_in[1];
    const float* gb  = (const float*)d_in[2];
    const float* thw = (const float*)d_in[3];
    const float* thb = (const float*)d_in[4];
    const float* phw = (const float*)d_in[5];
    const float* phb = (const float*)d_in[6];
    float* out = (float*)d_out;

    char* ws = (char*)d_ws;
    float* Sp = (float*)(ws + SP_OFF);
    float* Zp = (float*)(ws + ZP_OFF);
    float* M  = (float*)(ws + M_OFF);

    dim3 blk(256);
    proj_s<<<dim3(NBLK, BATCH), blk, 0, stream>>>(x, thw, thb, phw, phb, Sp, Zp);
    normalize_S<<<dim3(8, BATCH), blk, 0, stream>>>(Sp, Zp, M);
    attn_mfma<<<dim3(HWN / (128 * ACHUNK), BATCH), blk, 0, stream>>>(x, gw, gb, M, out);
}

// Round 8
// 262.779 us; speedup vs baseline: 5.3857x; 1.1030x over previous
//
#include <hip/hip_runtime.h>
#include <hip/hip_fp16.h>
#include <cstdint>
#include <cstddef>

#define BATCH 16
#define CH 64
#define HWN 65536
#define NBLK 64          // blocks per batch in proj_s (1024 px each)
#define PAD 72           // ushort row stride (144 B = 16B-aligned, conflict-light)
#define ACHUNK 8         // chunks (128 px) per attn block -> 1024 px/block

typedef __attribute__((ext_vector_type(8))) _Float16 half8;
typedef __attribute__((ext_vector_type(4))) float f32x4;

// ---------------- workspace layout (bytes) ----------------
static const size_t SP_OFF = 0;
static const size_t ZP_OFF = SP_OFF + (size_t)BATCH * NBLK * 4096 * 4;
static const size_t M_OFF  = ZP_OFF + (size_t)BATCH * NBLK * 4 * 64 * 4;

__device__ __forceinline__ half8 load_frag_f32(const float* p) {
    const float4 w0 = *(const float4*)p;
    const float4 w1 = *(const float4*)(p + 4);
    half8 f;
    f[0] = (_Float16)w0.x; f[1] = (_Float16)w0.y;
    f[2] = (_Float16)w0.z; f[3] = (_Float16)w0.w;
    f[4] = (_Float16)w1.x; f[5] = (_Float16)w1.y;
    f[6] = (_Float16)w1.z; f[7] = (_Float16)w1.w;
    return f;
}

// ---------------------------------------------------------------------------
// proj_s: theta/phi projections + S-GEMM + Z, 64-px chunks.
//   stage: x-tile (64px x 64ch) -> LDS f16 [px][ch] via coalesced float4
//   A    : T,P via MFMA (frags from xt); E=exp(T); El/Pl [ch][px] f16
//   B    : S += P * E^T (K=64), Z += E
// LDS 27.6 KB -> ~5 blocks/CU. 2 barriers/chunk (race-derivation in R8 notes).
// ---------------------------------------------------------------------------
__global__ __launch_bounds__(256) void proj_s(
    const float* __restrict__ x,
    const float* __restrict__ thw, const float* __restrict__ thb,
    const float* __restrict__ phw, const float* __restrict__ phb,
    float* __restrict__ Sp, float* __restrict__ Zp)
{
    __shared__ __align__(16) ushort xt[64 * PAD];   // 9.2 KB  [px][ch]
    __shared__ __align__(16) ushort El[64 * PAD];   // 9.2 KB  [ch][px]
    __shared__ __align__(16) ushort Pl[64 * PAD];   // 9.2 KB  [ch][px]
    const int b   = blockIdx.y;
    const int blk = blockIdx.x;
    const int tid = threadIdx.x;
    const int wid = tid >> 6;
    const int l   = tid & 63;
    const int lr  = l & 15;
    const int lg  = l >> 4;

    half8 Wf[2][4][2];
#pragma unroll
    for (int p = 0; p < 2; p++) {
        const float* wsrc = p ? phw : thw;
#pragma unroll
        for (int ot = 0; ot < 4; ot++)
#pragma unroll
            for (int g = 0; g < 2; g++)
                Wf[p][ot][g] = load_frag_f32(wsrc + (ot * 16 + lr) * 64 + g * 32 + lg * 8);
    }
    float bT[16], bP[16];
#pragma unroll
    for (int ot = 0; ot < 4; ot++)
#pragma unroll
        for (int i = 0; i < 4; i++) {
            bT[ot * 4 + i] = thb[ot * 16 + lg * 4 + i];
            bP[ot * 4 + i] = phb[ot * 16 + lg * 4 + i];
        }

    f32x4 Sacc[4];
#pragma unroll
    for (int j = 0; j < 4; j++) Sacc[j] = (f32x4){0.f, 0.f, 0.f, 0.f};
    float z[16];
#pragma unroll
    for (int k = 0; k < 16; k++) z[k] = 0.f;

    const float* xb = x + (size_t)b * CH * HWN;
    const int sch = tid >> 4;          // staging: base channel 0..15
    const int spx = (tid & 15) * 4;    // staging: px group

    for (int chk = 0; chk < 16; chk++) {
        const int nb = blk * 1024 + chk * 64;

        // ---- stage x-tile: 64ch x 64px f32 -> f16 [px][ch] ----
#pragma unroll
        for (int it = 0; it < 4; it++) {
            const int ch = sch + it * 16;
            const float4 v = *(const float4*)(xb + (size_t)ch * HWN + nb + spx);
            xt[(spx + 0) * PAD + ch] = __half_as_ushort(__float2half(v.x));
            xt[(spx + 1) * PAD + ch] = __half_as_ushort(__float2half(v.y));
            xt[(spx + 2) * PAD + ch] = __half_as_ushort(__float2half(v.z));
            xt[(spx + 3) * PAD + ch] = __half_as_ushort(__float2half(v.w));
        }
        __syncthreads();

        // ---- phase A: projections for this wave's 16 px ----
        const int ncol = wid * 16 + lr;
        half8 xf0 = *(const half8*)(xt + ncol * PAD + lg * 8);
        half8 xf1 = *(const half8*)(xt + ncol * PAD + 32 + lg * 8);
#pragma unroll
        for (int ot = 0; ot < 4; ot++) {
            const int off = (ot * 16 + lg * 4) * PAD + ncol;
            f32x4 acc = {bT[ot * 4 + 0], bT[ot * 4 + 1], bT[ot * 4 + 2], bT[ot * 4 + 3]};
            acc = __builtin_amdgcn_mfma_f32_16x16x32_f16(Wf[0][ot][0], xf0, acc, 0, 0, 0);
            acc = __builtin_amdgcn_mfma_f32_16x16x32_f16(Wf[0][ot][1], xf1, acc, 0, 0, 0);
#pragma unroll
            for (int i = 0; i < 4; i++) {
                float e = __expf(acc[i]);
                z[ot * 4 + i] += e;
                El[off + i * PAD] = __half_as_ushort(__float2half(e));
            }
            f32x4 pcc = {bP[ot * 4 + 0], bP[ot * 4 + 1], bP[ot * 4 + 2], bP[ot * 4 + 3]};
            pcc = __builtin_amdgcn_mfma_f32_16x16x32_f16(Wf[1][ot][0], xf0, pcc, 0, 0, 0);
            pcc = __builtin_amdgcn_mfma_f32_16x16x32_f16(Wf[1][ot][1], xf1, pcc, 0, 0, 0);
#pragma unroll
            for (int i = 0; i < 4; i++)
                Pl[off + i * PAD] = __half_as_ushort(__float2half(pcc[i]));
        }
        __syncthreads();

        // ---- phase B: S[c-slice,:] += P * E^T (K = 64 px) ----
        const ushort* arow = Pl + (wid * 16 + lr) * PAD;
#pragma unroll
        for (int g = 0; g < 2; g++) {
            const int coff = g * 32 + lg * 8;
            half8 af = *(const half8*)(arow + coff);
#pragma unroll
            for (int j = 0; j < 4; j++) {
                half8 bf = *(const half8*)(El + (j * 16 + lr) * PAD + coff);
                Sacc[j] = __builtin_amdgcn_mfma_f32_16x16x32_f16(af, bf, Sacc[j], 0, 0, 0);
            }
        }
        // no barrier needed here: next stage writes xt only (phase-A xt reads
        // completed before the A->B barrier); El/Pl rewrite is gated by the
        // post-stage barrier of the next chunk.
    }

    float* sp = Sp + (size_t)(b * NBLK + blk) * 4096;
#pragma unroll
    for (int j = 0; j < 4; j++)
#pragma unroll
        for (int i = 0; i < 4; i++)
            sp[(wid * 16 + lg * 4 + i) * 64 + j * 16 + lr] = Sacc[j][i];

#pragma unroll
    for (int k = 0; k < 16; k++) {
        float v = z[k];
        v += __shfl_xor(v, 1, 64);
        v += __shfl_xor(v, 2, 64);
        v += __shfl_xor(v, 4, 64);
        v += __shfl_xor(v, 8, 64);
        z[k] = v;
    }
    if (lr == 0) {
        float* zp = Zp + ((size_t)(b * NBLK + blk) * 4 + wid) * 64;
#pragma unroll
        for (int t = 0; t < 4; t++)
#pragma unroll
            for (int i = 0; i < 4; i++)
                zp[t * 16 + lg * 4 + i] = z[t * 4 + i];
    }
}

// ---------------------------------------------------------------------------
// Reduce split-K partials; M[b,c,d] = S[b,c,d] / Z[b,d]   (unchanged)
// ---------------------------------------------------------------------------
__global__ __launch_bounds__(256) void normalize_S(
    const float* __restrict__ Sp, const float* __restrict__ Zp,
    float* __restrict__ M)
{
    const int b   = blockIdx.y;
    const int sl  = blockIdx.x;
    const int tid = threadIdx.x;
    __shared__ float Zl[64];
    if (tid < 64) {
        float s = 0.f;
        const float* zp = Zp + (size_t)b * (NBLK * 4) * 64 + tid;
        for (int k = 0; k < NBLK * 4; k++) s += zp[(size_t)k * 64];
        Zl[tid] = 1.0f / s;
    }
    __syncthreads();
    const float* sp = Sp + (size_t)b * NBLK * 4096;
    float* mp = M + (size_t)b * 4096;
#pragma unroll
    for (int h = 0; h < 2; h++) {
        const int idx = sl * 512 + h * 256 + tid;
        float s = 0.f;
        for (int k = 0; k < NBLK; k++) s += sp[(size_t)k * 4096 + idx];
        mp[idx] = s * Zl[idx & 63];
    }
}

// ---------------------------------------------------------------------------
// attn: g-projection + channel softmax + att = M @ e + residual + lrelu.
// R5 phase-B structure (direct strided stores — measured faster than the
// Tl/float4 epilogue), with x staged to LDS f16 via coalesced float4:
//   stage: x-tile (64ch x 128px) -> xt[px][ch] f16
//   A    : gy via MFMA (frags from xt) -> softmax -> e -> El[px][ch]
//   B    : att = M @ e; residual read = f32 global (L2-hot); store.
// LDS 36.8 KB -> 4 blocks/CU. 2 barriers/chunk.
// ---------------------------------------------------------------------------
__global__ __launch_bounds__(256) void attn_mfma(
    const float* __restrict__ x,
    const float* __restrict__ gw, const float* __restrict__ gb,
    const float* __restrict__ M,
    float* __restrict__ out)
{
    __shared__ __align__(16) ushort xt[128 * PAD];   // 18.4 KB [px][ch]
    __shared__ __align__(16) ushort El[128 * PAD];   // 18.4 KB [px][ch]
    const int b   = blockIdx.y;
    const int tid = threadIdx.x;
    const int wid = tid >> 6;
    const int l   = tid & 63;
    const int lr  = l & 15;
    const int lg  = l >> 4;

    const float* xb = x + (size_t)b * CH * HWN;
    float* outb = out + (size_t)b * CH * HWN;

    half8 Gf[4][2];
#pragma unroll
    for (int ot = 0; ot < 4; ot++)
#pragma unroll
        for (int kg = 0; kg < 2; kg++)
            Gf[ot][kg] = load_frag_f32(gw + (ot * 16 + lr) * 64 + kg * 32 + lg * 8);
    float bG[16];
#pragma unroll
    for (int ot = 0; ot < 4; ot++)
#pragma unroll
        for (int i = 0; i < 4; i++) bG[ot * 4 + i] = gb[ot * 16 + lg * 4 + i];

    half8 Mf[4][2];
    const float* Mb = M + (size_t)b * 4096;
#pragma unroll
    for (int ct = 0; ct < 4; ct++)
#pragma unroll
        for (int kg = 0; kg < 2; kg++)
            Mf[ct][kg] = load_frag_f32(Mb + (ct * 16 + lr) * 64 + kg * 32 + lg * 8);

    const int sch = tid >> 5;          // staging: base channel 0..7
    const int spx = (tid & 31) * 4;    // staging: px group 0..124

    for (int chk = 0; chk < ACHUNK; chk++) {
        const int nb = blockIdx.x * (128 * ACHUNK) + chk * 128;

        // ---- stage x-tile: 64ch x 128px f32 -> f16 [px][ch] ----
#pragma unroll
        for (int it = 0; it < 8; it++) {
            const int ch = sch + it * 8;
            const float4 v = *(const float4*)(xb + (size_t)ch * HWN + nb + spx);
            xt[(spx + 0) * PAD + ch] = __half_as_ushort(__float2half(v.x));
            xt[(spx + 1) * PAD + ch] = __half_as_ushort(__float2half(v.y));
            xt[(spx + 2) * PAD + ch] = __half_as_ushort(__float2half(v.z));
            xt[(spx + 3) * PAD + ch] = __half_as_ushort(__float2half(v.w));
        }
        __syncthreads();

        float rz[2];
        // ---- phase A: g-projection + softmax, e -> El[px][ch] ----
#pragma unroll
        for (int nt = 0; nt < 2; nt++) {
            const int ncol = wid * 32 + nt * 16 + lr;
            half8 xf0 = *(const half8*)(xt + ncol * PAD + lg * 8);
            half8 xf1 = *(const half8*)(xt + ncol * PAD + 32 + lg * 8);

            float gy[4][4];
#pragma unroll
            for (int ot = 0; ot < 4; ot++) {
                f32x4 acc = {bG[ot * 4 + 0], bG[ot * 4 + 1], bG[ot * 4 + 2], bG[ot * 4 + 3]};
                acc = __builtin_amdgcn_mfma_f32_16x16x32_f16(Gf[ot][0], xf0, acc, 0, 0, 0);
                acc = __builtin_amdgcn_mfma_f32_16x16x32_f16(Gf[ot][1], xf1, acc, 0, 0, 0);
#pragma unroll
                for (int i = 0; i < 4; i++) gy[ot][i] = acc[i];
            }
            float m = gy[0][0];
#pragma unroll
            for (int ot = 0; ot < 4; ot++)
#pragma unroll
                for (int i = 0; i < 4; i++) m = fmaxf(m, gy[ot][i]);
            m = fmaxf(m, __shfl_xor(m, 16, 64));
            m = fmaxf(m, __shfl_xor(m, 32, 64));

            float zs = 0.f;
            ushort* erow = El + ncol * PAD;
#pragma unroll
            for (int ot = 0; ot < 4; ot++) {
                float e0 = __expf(gy[ot][0] - m);
                float e1 = __expf(gy[ot][1] - m);
                float e2 = __expf(gy[ot][2] - m);
                float e3 = __expf(gy[ot][3] - m);
                zs += e0 + e1 + e2 + e3;
                uint2 pk;
                pk.x = (uint)__half_as_ushort(__float2half(e0)) |
                       ((uint)__half_as_ushort(__float2half(e1)) << 16);
                pk.y = (uint)__half_as_ushort(__float2half(e2)) |
                       ((uint)__half_as_ushort(__float2half(e3)) << 16);
                *(uint2*)(erow + ot * 16 + lg * 4) = pk;
            }
            zs += __shfl_xor(zs, 16, 64);
            zs += __shfl_xor(zs, 32, 64);
            rz[nt] = 1.0f / zs;
        }

        // ---- phase B: att = M @ e; 1/Z; residual (L2-hot f32); lrelu ----
#pragma unroll
        for (int nt = 0; nt < 2; nt++) {
            const int ncol = wid * 32 + nt * 16 + lr;
            const ushort* brow = El + ncol * PAD;      // wave-private row
            half8 bf0 = *(const half8*)(brow + lg * 8);
            half8 bf1 = *(const half8*)(brow + 32 + lg * 8);
            const float sc = rz[nt];
#pragma unroll
            for (int ct = 0; ct < 4; ct++) {
                f32x4 acc = {0.f, 0.f, 0.f, 0.f};
                acc = __builtin_amdgcn_mfma_f32_16x16x32_f16(Mf[ct][0], bf0, acc, 0, 0, 0);
                acc = __builtin_amdgcn_mfma_f32_16x16x32_f16(Mf[ct][1], bf1, acc, 0, 0, 0);
#pragma unroll
                for (int i = 0; i < 4; i++) {
                    const size_t off = (size_t)(ct * 16 + lg * 4 + i) * HWN + nb + ncol;
                    float v = xb[off] + acc[i] * sc;
                    outb[off] = (v >= 0.f) ? v : 0.1f * v;
                }
            }
        }
        __syncthreads();   // xt/El safe to rewrite next chunk
    }
}

// ---------------------------------------------------------------------------
extern "C" void kernel_launch(void* const* d_in, const int* in_sizes, int n_in,
                              void* d_out, int out_size, void* d_ws, size_t ws_size,
                              hipStream_t stream)
{
    const float* x   = (const float*)d_in[0];
    const float* gw  = (const float*)d_in[1];
    const float* gb  = (const float*)d_in[2];
    const float* thw = (const float*)d_in[3];
    const float* thb = (const float*)d_in[4];
    const float* phw = (const float*)d_in[5];
    const float* phb = (const float*)d_in[6];
    float* out = (float*)d_out;

    char* ws = (char*)d_ws;
    float* Sp = (float*)(ws + SP_OFF);
    float* Zp = (float*)(ws + ZP_OFF);
    float* M  = (float*)(ws + M_OFF);

    dim3 blk(256);
    proj_s<<<dim3(NBLK, BATCH), blk, 0, stream>>>(x, thw, thb, phw, phb, Sp, Zp);
    normalize_S<<<dim3(8, BATCH), blk, 0, stream>>>(Sp, Zp, M);
    attn_mfma<<<dim3(HWN / (128 * ACHUNK), BATCH), blk, 0, stream>>>(x, gw, gb, M, out);
}